// Round 8
// baseline (7474.210 us; speedup 1.0000x reference)
//
#include <hip/hip_runtime.h>
#include <hip/hip_bf16.h>
#include <stdint.h>

typedef __attribute__((ext_vector_type(8))) short short8;   // 8 bf16 (4 VGPRs) MFMA frag
typedef __attribute__((ext_vector_type(4))) float f32x4;    // MFMA acc
typedef unsigned long long u64;
typedef unsigned int u32;

// ---------- helpers ----------
__device__ __forceinline__ float bf2f(unsigned short s){
  union { float f; u32 u; } v; v.u = ((u32)s) << 16; return v.f;
}
__device__ __forceinline__ unsigned short f2bf(float f){
  u32 u = __float_as_uint(f);
  u32 r = (u + 0x7fffu + ((u >> 16) & 1u)) >> 16;   // RNE
  return (unsigned short)r;
}
__device__ __forceinline__ float sigm(float x){ return 1.0f / (1.0f + __expf(-x)); }
__device__ __forceinline__ float tanh_(float x){ return 1.0f - 2.0f/(__expf(2.0f*x) + 1.0f); }
__device__ __forceinline__ u64 pack4(float a, float b, float c, float d){
  return (u64)f2bf(a) | ((u64)f2bf(b)<<16) | ((u64)f2bf(c)<<32) | ((u64)f2bf(d)<<48);
}
// async global->LDS, 16B per lane; dest must be wave-uniform base + lane*16
__device__ __forceinline__ void gl_lds16(const void* g, void* l){
  __builtin_amdgcn_global_load_lds(
      (const __attribute__((address_space(1))) unsigned int*)g,
      (__attribute__((address_space(3))) unsigned int*)l, 16, 0, 0);
}

// =====================================================================
// K0a: pack weights into MFMA fragment layout (bf16)
//  frag convention (16x16x32): lane l elem j -> [nonK = l&15][k = (l>>4)*8 + j]
// pack1: w_hh1 (768x256): 8 wave-slots s, slot s owns units [32s,32s+32);
//        frags f = s*48 + m*8 + kt, m: 0,1=r(sub0,1) 2,3=z 4,5=n
// pack2: [w_ih2f; w_ih2b] as 768 G-rows: slot s owns G [96s,96s+96)
// pack3: per-dir w_hh2 (384x128), 8 waves, wave w owns unit block 16w
// =====================================================================
__global__ void k_pack(const float* __restrict__ w_hh1,
                       const float* __restrict__ w_ih2f, const float* __restrict__ w_ih2b,
                       const float* __restrict__ w_hh2f, const float* __restrict__ w_hh2b,
                       unsigned short* __restrict__ pack1,
                       unsigned short* __restrict__ pack2,
                       unsigned short* __restrict__ pack3)
{
  int tid = blockIdx.x*256 + threadIdx.x;
  const float* src;
  unsigned short* dst;
  long idx;
  if (tid < 24576){
    int f = tid>>6, l = tid&63;
    int s = f/48, rem = f%48, m = rem>>3, kt = rem&7;
    int g  = ((m>>1)<<8) + (s<<5) + ((m&1)<<4) + (l&15);
    int kb = (kt<<5) + ((l>>4)<<3);
    src = w_hh1 + (size_t)g*256 + kb;
    dst = pack1; idx = tid;
  } else if (tid < 49152){
    int t2 = tid - 24576;
    int f = t2>>6, l = t2&63;
    int s = f/48, rem = f%48, m = rem>>3, kt = rem&7;
    int G  = 96*s + (m<<4) + (l&15);
    int kb = (kt<<5) + ((l>>4)<<3);
    const float* W = (G < 384) ? w_ih2f : w_ih2b;
    src = W + (size_t)(G % 384)*256 + kb;
    dst = pack2; idx = t2;
  } else {
    int t3 = tid - 49152;
    int f = t3>>6, l = t3&63;
    int dir = f/96, r96 = f%96, w = r96/12, r12 = r96%12, m = r12>>2, kt = r12&3;
    int Grow = (m<<7) + (w<<4) + (l&15);
    int kb = (kt<<5) + ((l>>4)<<3);
    src = (dir ? w_hh2b : w_hh2f) + (size_t)Grow*128 + kb;
    dst = pack3; idx = t3;
  }
  u64 lo = (u64)f2bf(src[0]) | ((u64)f2bf(src[1])<<16) | ((u64)f2bf(src[2])<<32) | ((u64)f2bf(src[3])<<48);
  u64 hi = (u64)f2bf(src[4]) | ((u64)f2bf(src[5])<<16) | ((u64)f2bf(src[6])<<32) | ((u64)f2bf(src[7])<<48);
  *(u64*)(dst + (size_t)idx*8)     = lo;
  *(u64*)(dst + (size_t)idx*8 + 4) = hi;
}

// =====================================================================
// K0b: xgV[v][g] = emb[v,:]·w_ih1[g,:] + b_ih1[g] + (g<512 ? b_hh1[g] : 0)
// Also zeroes the 16 handshake flags (runs before k_scan1 every launch).
// =====================================================================
__global__ void k_xgv(const float* __restrict__ emb, const float* __restrict__ w_ih1,
                      const float* __restrict__ b_ih1, const float* __restrict__ b_hh1,
                      float* __restrict__ xgV, u32* __restrict__ flg)
{
  int tid = blockIdx.x*256 + threadIdx.x;        // 98304 total
  if (tid < 16) flg[tid] = 0;
  int v = tid / 768, g = tid % 768;
  float s = b_ih1[g] + (g < 512 ? b_hh1[g] : 0.0f);
  const f32x4* e4 = (const f32x4*)(emb   + (size_t)v*312);
  const f32x4* w4 = (const f32x4*)(w_ih1 + (size_t)g*312);
  #pragma unroll 4
  for (int i=0;i<78;i++){
    f32x4 a = e4[i], b = w4[i];
    s += a[0]*b[0] + a[1]*b[1] + a[2]*b[2] + a[3]*b[3];
  }
  xgV[tid] = s;
}

// =====================================================================
// K1: layer-1 scan, unit-split pairs. 16 wgs x 256 thr (4 waves).
// wg = (group g, half p): batches [16g,16g+16), units [128p,128p+128).
// Wave w owns units [128p+32w, +32) = slot s=4p+w of pack1. Weights =
// 192 VGPRs/lane, resident under the 256-reg cap of a 256-thr WG
// (r7 post-mortem: cap = 65536/threads; only 256-thr blocks allow 256).
// Halves exchange h (bf16) + LN partials per step via device-scope
// atomics (Infinity-Cache coherent, no XCD assumption): per-wave
// vmcnt(0) -> lane0 fetch_add(flag); reader polls flag >= 4(t+1);
// double-buffered slots; flags zeroed by k_xgv each launch.
// D = mfma(Wfrag, hfrag): row=gate (lane>>4)*4+j, col=batch lane&15.
// =====================================================================
__launch_bounds__(256)
__global__ void k_scan1(const int* __restrict__ token,
                        const float* __restrict__ xgV,
                        const unsigned short* __restrict__ pack1,
                        const float* __restrict__ b_hh1,
                        const float* __restrict__ ln_g, const float* __restrict__ ln_b,
                        unsigned short* __restrict__ hn,
                        u64* __restrict__ hx, u64* __restrict__ px,
                        u32* __restrict__ flg)
{
  __shared__ __align__(16) char hb[2][8192];     // [32 chunk][16 batch][8 bf16] (full 256 units)
  __shared__ __align__(16) char lxg[2][24576];   // [96 chunk][16 batch][4 f32] (own half's gates)
  __shared__ __align__(16) float lng[128];
  __shared__ __align__(16) float lnb[128];
  __shared__ __align__(16) float bnl[128];       // b_hh1 n-part, own half
  __shared__ __align__(8)  float2 scr[4][16];    // per-wave LN partials

  const int tid = threadIdx.x;
  const int w = tid>>6, lane = tid&63, hi = lane>>4, col = lane&15;
  const int g = blockIdx.x >> 1, p = blockIdx.x & 1;
  const int s = p*4 + w;                         // pack1 wave-slot
  const int b0 = g*16;
  const int myf = g*2 + p, otf = g*2 + (1-p);    // flag indices

  // persistent weight fragments: 6 Mtiles (r0,r1,z0,z1,n0,n1) x 8 Ktiles = 192 VGPRs
  short8 wf[6][8];
  #pragma unroll
  for (int m=0;m<6;m++)
    #pragma unroll
    for (int kt=0;kt<8;kt++)
      wf[m][kt] = *(const short8*)(pack1 + (size_t)((s*48 + m*8 + kt)*64 + lane)*8);

  if (tid < 128){ lng[tid] = ln_g[128*p + tid]; bnl[tid] = b_hh1[512 + 128*p + tid]; }
  else          { lnb[tid-128] = ln_b[128*p + tid-128]; }
  for (int i = tid; i < 2048; i += 256) ((u32*)hb[0])[i] = 0;
  f32x4 hr[2]; hr[0] = (f32x4){0,0,0,0}; hr[1] = (f32x4){0,0,0,0};

  // stage own half's xg(t): lxg[c][b] <- xgV[tok(b)][sect(c>>5)*256 + 128p + (c&31)*4]
  auto stage = [&](int tt, int buf){
    int tok = token[tt*128 + b0 + (tid & 15)];
    const char* srcb = (const char*)xgV + (size_t)tok*3072 + p*512;
    char* dst = lxg[buf] + (tid>>4)*256 + (tid&15)*16;
    #pragma unroll
    for (int k=0;k<6;k++){
      int c = (tid>>4) + 16*k;
      gl_lds16(srcb + (c>>5)*1024 + (c&31)*16, dst + k*4096);
    }
  };
  stage(0, 0);
  __syncthreads();

  for (int t=0; t<1024; t++){
    const int cur = t & 1, nxt = cur ^ 1;
    if (t < 1023) stage(t+1, nxt);

    f32x4 acc[6];
    #pragma unroll
    for (int m=0;m<6;m++) acc[m] = (f32x4){0,0,0,0};
    #pragma unroll
    for (int kt=0;kt<8;kt++){
      short8 hf = *(const short8*)(hb[cur] + ((kt<<2)+hi)*256 + (col<<4));
      #pragma unroll
      for (int m=0;m<6;m++)
        acc[m] = __builtin_amdgcn_mfma_f32_16x16x32_bf16(wf[m][kt], hf, acc[m], 0, 0, 0);
    }

    float s1 = 0.f, s2 = 0.f;
    u64 pkv[2];
    #pragma unroll
    for (int nt=0;nt<2;nt++){
      const int lu = (w<<5) + (nt<<4) + (hi<<2);  // local unit base (0..124)
      const char* xb = lxg[cur] + (col<<4);
      f32x4 xr  = *(const f32x4*)(xb + (size_t)(lu>>2)*256);
      f32x4 xz  = *(const f32x4*)(xb + (size_t)((lu>>2)+32)*256);
      f32x4 xn  = *(const f32x4*)(xb + (size_t)((lu>>2)+64)*256);
      f32x4 bn4 = *(const f32x4*)(bnl + lu);
      #pragma unroll
      for (int j=0;j<4;j++){
        float r  = sigm(xr[j] + acc[nt][j]);      // b_ih + b_hh_r/z folded in xgV
        float z  = sigm(xz[j] + acc[2+nt][j]);
        float nn = tanh_(xn[j] + r*(acc[4+nt][j] + bn4[j]));
        float h  = nn + z*(hr[nt][j] - nn);
        hr[nt][j] = h;
        s1 += h; s2 += h*h;
      }
      pkv[nt] = pack4(hr[nt][0], hr[nt][1], hr[nt][2], hr[nt][3]);
    }
    // publish own half early (device-scope atomics -> coherent at IC)
    {
      size_t hxb = ((((size_t)cur*8 + g)*2 + p)*16 + col)*32;
      __hip_atomic_store(hx + hxb + ((w<<3)     + hi), pkv[0],
                         __ATOMIC_RELAXED, __HIP_MEMORY_SCOPE_AGENT);
      __hip_atomic_store(hx + hxb + ((w<<3) + 4 + hi), pkv[1],
                         __ATOMIC_RELAXED, __HIP_MEMORY_SCOPE_AGENT);
    }
    // own half into hb[nxt]
    #pragma unroll
    for (int nt=0;nt<2;nt++){
      int u = 128*p + (w<<5) + (nt<<4) + (hi<<2);
      *(u64*)(hb[nxt] + (u>>3)*256 + (col<<4) + ((hi&1)<<3)) = pkv[nt];
    }
    s1 += __shfl_xor(s1, 16); s1 += __shfl_xor(s1, 32);
    s2 += __shfl_xor(s2, 16); s2 += __shfl_xor(s2, 32);
    if (hi == 0) scr[w][col] = make_float2(s1, s2);
    __syncthreads();                              // barrier1: scr ready

    float S1h = 0.f, S2h = 0.f;
    #pragma unroll
    for (int ww=0; ww<4; ww++){ float2 v = scr[ww][col]; S1h += v.x; S2h += v.y; }
    if (tid < 16){                                // w==0,hi==0,col==tid
      union{ float f[2]; u64 u; } pv; pv.f[0] = S1h; pv.f[1] = S2h;
      __hip_atomic_store(px + (((size_t)cur*8 + g)*2 + p)*16 + col, pv.u,
                         __ATOMIC_RELAXED, __HIP_MEMORY_SCOPE_AGENT);
    }
    asm volatile("s_waitcnt vmcnt(0)" ::: "memory");   // wave's publishes complete
    if (lane == 0)
      __hip_atomic_fetch_add(&flg[myf], 1u, __ATOMIC_RELAXED, __HIP_MEMORY_SCOPE_AGENT);
    const u32 need = 4u*(u32)(t+1);
    while (__hip_atomic_load(&flg[otf], __ATOMIC_RELAXED, __HIP_MEMORY_SCOPE_AGENT) < need)
      __builtin_amdgcn_s_sleep(1);

    // read pair's half + partials
    size_t oxb = ((((size_t)cur*8 + g)*2 + (1-p))*16 + col)*32;
    u64 oh0 = __hip_atomic_load(hx + oxb + ((w<<3)     + hi),
                                __ATOMIC_RELAXED, __HIP_MEMORY_SCOPE_AGENT);
    u64 oh1 = __hip_atomic_load(hx + oxb + ((w<<3) + 4 + hi),
                                __ATOMIC_RELAXED, __HIP_MEMORY_SCOPE_AGENT);
    u64 pxo = __hip_atomic_load(px + (((size_t)cur*8 + g)*2 + (1-p))*16 + col,
                                __ATOMIC_RELAXED, __HIP_MEMORY_SCOPE_AGENT);
    {
      int u0 = 128*(1-p) + (w<<5) + (hi<<2);
      *(u64*)(hb[nxt] + (u0>>3)*256 + (col<<4) + ((hi&1)<<3)) = oh0;
      int u1 = u0 + 16;
      *(u64*)(hb[nxt] + (u1>>3)*256 + (col<<4) + ((hi&1)<<3)) = oh1;
    }
    union{ u64 u; float f[2]; } pv2; pv2.u = pxo;
    float S1 = S1h + pv2.f[0], S2 = S2h + pv2.f[1];
    float mu  = S1 * (1.0f/256.0f);
    float var = S2 * (1.0f/256.0f) - mu*mu;
    float rs  = rsqrtf(var + 256.0f);             // faithful eps=256
    #pragma unroll
    for (int nt=0;nt<2;nt++){
      const int lu = (w<<5) + (nt<<4) + (hi<<2);
      f32x4 g4 = *(const f32x4*)(lng + lu);
      f32x4 e4 = *(const f32x4*)(lnb + lu);
      u64 pk = pack4((hr[nt][0]-mu)*rs*g4[0] + e4[0],
                     (hr[nt][1]-mu)*rs*g4[1] + e4[1],
                     (hr[nt][2]-mu)*rs*g4[2] + e4[2],
                     (hr[nt][3]-mu)*rs*g4[3] + e4[3]);
      *(u64*)(hn + (size_t)(t*128 + b0 + col)*256 + 128*p + lu) = pk;
    }
    __syncthreads();                              // hb[nxt] complete
  }
}

// =====================================================================
// K3: xg2 = hn @ [w_ih2f; w_ih2b]^T. 512 wgs x 256 thr (4 waves).
// dir = blockIdx&1; wave w = slot s=4*dir+w of pack2 (96 G-rows each);
// 192 weight VGPRs/lane, resident under the 256-thr cap. 32 TB-tiles/wg.
// =====================================================================
__launch_bounds__(256)
__global__ void k_k3(const unsigned short* __restrict__ hn,
                     const unsigned short* __restrict__ pack2,
                     unsigned short* __restrict__ xg2f,
                     unsigned short* __restrict__ xg2b)
{
  const int tid = threadIdx.x;
  const int w = tid>>6, lane = tid&63, hi = lane>>4, col = lane&15;
  const int dir = blockIdx.x & 1;
  const int s = dir*4 + w;
  short8 wf[6][8];
  #pragma unroll
  for (int m=0;m<6;m++)
    #pragma unroll
    for (int kt=0;kt<8;kt++)
      wf[m][kt] = *(const short8*)(pack2 + (size_t)((s*48 + m*8 + kt)*64 + lane)*8);
  unsigned short* dst = dir ? xg2b : xg2f;

  for (int it=0; it<32; it++){
    int tb0 = (blockIdx.x>>1)*512 + it*16;
    const unsigned short* hrow = hn + (size_t)(tb0 + col)*256;
    f32x4 acc[6];
    #pragma unroll
    for (int m=0;m<6;m++) acc[m] = (f32x4){0,0,0,0};
    #pragma unroll
    for (int kt=0;kt<8;kt++){
      short8 hf = *(const short8*)(hrow + (kt<<5) + (hi<<3));
      #pragma unroll
      for (int m=0;m<6;m++)
        acc[m] = __builtin_amdgcn_mfma_f32_16x16x32_bf16(wf[m][kt], hf, acc[m], 0, 0, 0);
    }
    #pragma unroll
    for (int m=0;m<6;m++){
      int Gl = 96*w + (m<<4) + (hi<<2);
      u64 pk = pack4(acc[m][0], acc[m][1], acc[m][2], acc[m][3]);
      *(u64*)(dst + (size_t)(tb0 + col)*384 + Gl) = pk;
    }
  }
}

// =====================================================================
// K4: layer-2 scans, fwd+bwd concurrent. 16 wgs (8 fwd, 8 bwd) x 8 waves.
// Wave w owns hidden block 16w; w_hh2 in 48 VGPRs/lane (fits 128 cap). fp32 out.
// =====================================================================
__launch_bounds__(512)
__global__ void k_scan2(const unsigned short* __restrict__ xg2f,
                        const unsigned short* __restrict__ xg2b,
                        const unsigned short* __restrict__ pack3,
                        const float* __restrict__ b_ih2f, const float* __restrict__ b_hh2f,
                        const float* __restrict__ b_ih2b, const float* __restrict__ b_hh2b,
                        float* __restrict__ out)
{
  __shared__ __align__(16) char hb[2][4096];     // [16 chunk][16 batch][8 bf16]
  const int tid = threadIdx.x;
  const int w = tid>>6, lane = tid&63, hi = lane>>4, col = lane&15;
  const int blk = blockIdx.x;
  const int dir = blk >> 3;
  const int b0  = (blk & 7) * 16;
  const unsigned short* xg = dir ? xg2b : xg2f;
  const float* bi = dir ? b_ih2b : b_ih2f;
  const float* bh = dir ? b_hh2b : b_hh2f;

  short8 wf[3][4];
  #pragma unroll
  for (int m=0;m<3;m++)
    #pragma unroll
    for (int kt=0;kt<4;kt++)
      wf[m][kt] = *(const short8*)(pack3 + (size_t)(((dir*96 + w*12 + (m<<2) + kt))*64 + lane)*8);

  const int u = (w<<4) + (hi<<2);
  f32x4 bir = *(const f32x4*)(bi + u),        bhr = *(const f32x4*)(bh + u);
  f32x4 biz = *(const f32x4*)(bi + 128 + u),  bhz = *(const f32x4*)(bh + 128 + u);
  f32x4 bin = *(const f32x4*)(bi + 256 + u),  bhn = *(const f32x4*)(bh + 256 + u);
  f32x4 bcr = bir + bhr, bcz = biz + bhz;

  for (int i = tid; i < 1024; i += 512) ((u32*)hb[0])[i] = 0;
  f32x4 hcur = (f32x4){0,0,0,0};

  int te0 = dir ? 1023 : 0;
  const unsigned short* p0 = xg + (size_t)(te0*128 + b0 + col)*384;
  u64 xr_n = *(const u64*)(p0 + u);
  u64 xz_n = *(const u64*)(p0 + 128 + u);
  u64 xn_n = *(const u64*)(p0 + 256 + u);
  __syncthreads();

  for (int t=0; t<1024; t++){
    const int cur = t & 1, nxt = cur ^ 1;
    u64 xr = xr_n, xz = xz_n, xn = xn_n;
    if (t < 1023){
      int te1 = dir ? (1022 - t) : (t + 1);
      const unsigned short* p = xg + (size_t)(te1*128 + b0 + col)*384;
      xr_n = *(const u64*)(p + u);
      xz_n = *(const u64*)(p + 128 + u);
      xn_n = *(const u64*)(p + 256 + u);
    }
    f32x4 acc[3];
    #pragma unroll
    for (int m=0;m<3;m++) acc[m] = (f32x4){0,0,0,0};
    #pragma unroll
    for (int kt=0;kt<4;kt++){
      short8 hf = *(const short8*)(hb[cur] + ((kt<<2)+hi)*256 + (col<<4));
      #pragma unroll
      for (int m=0;m<3;m++)
        acc[m] = __builtin_amdgcn_mfma_f32_16x16x32_bf16(wf[m][kt], hf, acc[m], 0, 0, 0);
    }
    const int te = dir ? (1023 - t) : t;
    f32x4 hnew;
    #pragma unroll
    for (int j=0;j<4;j++){
      float r  = sigm(bf2f((unsigned short)(xr >> (16*j))) + bcr[j] + acc[0][j]);
      float z  = sigm(bf2f((unsigned short)(xz >> (16*j))) + bcz[j] + acc[1][j]);
      float nn = tanh_(bf2f((unsigned short)(xn >> (16*j))) + bin[j] + r*(acc[2][j] + bhn[j]));
      hnew[j] = nn + z*(hcur[j] - nn);
    }
    hcur = hnew;
    *(f32x4*)(out + (size_t)(te*128 + b0 + col)*256 + dir*128 + u) = hnew;
    u64 pk = pack4(hnew[0], hnew[1], hnew[2], hnew[3]);
    *(u64*)(hb[nxt] + ((u>>3))*256 + (col<<4) + ((hi&1)<<3)) = pk;
    __syncthreads();
  }
}

// =====================================================================
extern "C" void kernel_launch(void* const* d_in, const int* in_sizes, int n_in,
                              void* d_out, int out_size, void* d_ws, size_t ws_size,
                              hipStream_t stream)
{
  (void)in_sizes; (void)n_in; (void)out_size; (void)ws_size;
  const int*   token  = (const int*)  d_in[0];
  const float* emb    = (const float*)d_in[1];
  const float* w_ih1  = (const float*)d_in[2];
  const float* w_hh1  = (const float*)d_in[3];
  const float* b_ih1  = (const float*)d_in[4];
  const float* b_hh1  = (const float*)d_in[5];
  const float* ln_g   = (const float*)d_in[6];
  const float* ln_b   = (const float*)d_in[7];
  const float* w_ih2f = (const float*)d_in[8];
  const float* w_hh2f = (const float*)d_in[9];
  const float* b_ih2f = (const float*)d_in[10];
  const float* b_hh2f = (const float*)d_in[11];
  const float* w_ih2b = (const float*)d_in[12];
  const float* w_hh2b = (const float*)d_in[13];
  const float* b_ih2b = (const float*)d_in[14];
  const float* b_hh2b = (const float*)d_in[15];
  float* out = (float*)d_out;

  char* ws = (char*)d_ws;
  unsigned short* hn    = (unsigned short*)(ws);              //  67,108,864 B
  unsigned short* xg2f  = (unsigned short*)(ws + 67108864);   // 100,663,296 B
  unsigned short* xg2b  = (unsigned short*)(ws + 167772160);  // 100,663,296 B
  // xgV (f32, 393,216 B) aliases the START of the xg2b region: consumed by
  // k_scan1 before k_k3 writes xg2b.
  float*          xgV   = (float*)(ws + 167772160);
  unsigned short* pack1 = (unsigned short*)(ws + 268632064);  //     393,216 B
  unsigned short* pack2 = (unsigned short*)(ws + 269025280);  //     393,216 B
  unsigned short* pack3 = (unsigned short*)(ws + 269418496);  //     196,608 B
  u64*            hx    = (u64*)          (ws + 269615104);   //     131,072 B
  u64*            px    = (u64*)          (ws + 269746176);   //       4,096 B
  u32*            flg   = (u32*)          (ws + 269750272);   //          64 B

  hipLaunchKernelGGL(k_pack,  dim3(240), dim3(256), 0, stream,
                     w_hh1, w_ih2f, w_ih2b, w_hh2f, w_hh2b, pack1, pack2, pack3);
  hipLaunchKernelGGL(k_xgv,   dim3(384), dim3(256), 0, stream,
                     emb, w_ih1, b_ih1, b_hh1, xgV, flg);
  hipLaunchKernelGGL(k_scan1, dim3(16),  dim3(256), 0, stream,
                     token, xgV, pack1, b_hh1, ln_g, ln_b, hn, hx, px, flg);
  hipLaunchKernelGGL(k_k3,    dim3(512), dim3(256), 0, stream,
                     hn, pack2, xg2f, xg2b);
  hipLaunchKernelGGL(k_scan2, dim3(16),  dim3(512), 0, stream,
                     xg2f, xg2b, pack3, b_ih2f, b_hh2f, b_ih2b, b_hh2b, out);
}

// Round 9
// 7426.021 us; speedup vs baseline: 1.0065x; 1.0065x over previous
//
#include <hip/hip_runtime.h>
#include <hip/hip_bf16.h>
#include <stdint.h>

typedef __attribute__((ext_vector_type(8))) short short8;   // 8 bf16 (4 VGPRs) MFMA frag
typedef __attribute__((ext_vector_type(4))) float f32x4;    // MFMA acc
typedef unsigned long long u64;
typedef unsigned int u32;

// ---------- helpers ----------
__device__ __forceinline__ float bf2f(unsigned short s){
  union { float f; u32 u; } v; v.u = ((u32)s) << 16; return v.f;
}
__device__ __forceinline__ unsigned short f2bf(float f){
  u32 u = __float_as_uint(f);
  u32 r = (u + 0x7fffu + ((u >> 16) & 1u)) >> 16;   // RNE
  return (unsigned short)r;
}
__device__ __forceinline__ float sigm(float x){ return 1.0f / (1.0f + __expf(-x)); }
__device__ __forceinline__ float tanh_(float x){ return 1.0f - 2.0f/(__expf(2.0f*x) + 1.0f); }
__device__ __forceinline__ u64 pack4(float a, float b, float c, float d){
  return (u64)f2bf(a) | ((u64)f2bf(b)<<16) | ((u64)f2bf(c)<<32) | ((u64)f2bf(d)<<48);
}
// async global->LDS, 16B per lane; dest must be wave-uniform base + lane*16
__device__ __forceinline__ void gl_lds16(const void* g, void* l){
  __builtin_amdgcn_global_load_lds(
      (const __attribute__((address_space(1))) unsigned int*)g,
      (__attribute__((address_space(3))) unsigned int*)l, 16, 0, 0);
}

// =====================================================================
// K0a: pack weights into MFMA fragment layout (bf16)
//  frag convention (16x16x32): lane l elem j -> [nonK = l&15][k = (l>>4)*8 + j]
// pack1: w_hh1 (768x256): 4 wave-slots, slot w owns units [64w,64w+64);
//        frag f = w*96 + (G*4+s)*8 + kt  (G=0,1,2 = r,z,n; s=unit sub-block)
//        row g = G*256 + 64w + 16s + (l&15); k = kt*32 + (l>>4)*8
// pack2: [w_ih2f; w_ih2b] as 768 G-rows: 8 slots, slot s owns G [96s,96s+96)
// pack3: per-dir w_hh2 (384x128), 8 waves, wave w owns unit block 16w
// =====================================================================
__global__ void k_pack(const float* __restrict__ w_hh1,
                       const float* __restrict__ w_ih2f, const float* __restrict__ w_ih2b,
                       const float* __restrict__ w_hh2f, const float* __restrict__ w_hh2b,
                       unsigned short* __restrict__ pack1,
                       unsigned short* __restrict__ pack2,
                       unsigned short* __restrict__ pack3)
{
  int tid = blockIdx.x*256 + threadIdx.x;
  const float* src;
  unsigned short* dst;
  long idx;
  if (tid < 24576){
    int f = tid>>6, l = tid&63;
    int w = f/96, rem = f%96, kt = rem&7, ms = rem>>3, G = ms>>2, s = ms&3;
    int g  = (G<<8) + (w<<6) + (s<<4) + (l&15);
    int kb = (kt<<5) + ((l>>4)<<3);
    src = w_hh1 + (size_t)g*256 + kb;
    dst = pack1; idx = tid;
  } else if (tid < 49152){
    int t2 = tid - 24576;
    int f = t2>>6, l = t2&63;
    int s = f/48, rem = f%48, m = rem>>3, kt = rem&7;
    int G  = 96*s + (m<<4) + (l&15);
    int kb = (kt<<5) + ((l>>4)<<3);
    const float* W = (G < 384) ? w_ih2f : w_ih2b;
    src = W + (size_t)(G % 384)*256 + kb;
    dst = pack2; idx = t2;
  } else {
    int t3 = tid - 49152;
    int f = t3>>6, l = t3&63;
    int dir = f/96, r96 = f%96, w = r96/12, r12 = r96%12, m = r12>>2, kt = r12&3;
    int Grow = (m<<7) + (w<<4) + (l&15);
    int kb = (kt<<5) + ((l>>4)<<3);
    src = (dir ? w_hh2b : w_hh2f) + (size_t)Grow*128 + kb;
    dst = pack3; idx = t3;
  }
  u64 lo = (u64)f2bf(src[0]) | ((u64)f2bf(src[1])<<16) | ((u64)f2bf(src[2])<<32) | ((u64)f2bf(src[3])<<48);
  u64 hi = (u64)f2bf(src[4]) | ((u64)f2bf(src[5])<<16) | ((u64)f2bf(src[6])<<32) | ((u64)f2bf(src[7])<<48);
  *(u64*)(dst + (size_t)idx*8)     = lo;
  *(u64*)(dst + (size_t)idx*8 + 4) = hi;
}

// =====================================================================
// K0b: xgV[v][g] = emb[v,:]·w_ih1[g,:] + b_ih1[g] + (g<512 ? b_hh1[g] : 0)
// =====================================================================
__global__ void k_xgv(const float* __restrict__ emb, const float* __restrict__ w_ih1,
                      const float* __restrict__ b_ih1, const float* __restrict__ b_hh1,
                      float* __restrict__ xgV)
{
  int tid = blockIdx.x*256 + threadIdx.x;        // 98304 total
  int v = tid / 768, g = tid % 768;
  float s = b_ih1[g] + (g < 512 ? b_hh1[g] : 0.0f);
  const f32x4* e4 = (const f32x4*)(emb   + (size_t)v*312);
  const f32x4* w4 = (const f32x4*)(w_ih1 + (size_t)g*312);
  #pragma unroll 4
  for (int i=0;i<78;i++){
    f32x4 a = e4[i], b = w4[i];
    s += a[0]*b[0] + a[1]*b[1] + a[2]*b[2] + a[3]*b[3];
  }
  xgV[tid] = s;
}

// =====================================================================
// K1: layer-1 scan. 8 wgs x 256 thr (4 waves = 1 wave/SIMD -> 512-reg
// budget/wave, r8 evidence: unified RA allocates past 256 total).
// wg owns batches [16g,16g+16); wave w owns units [64w,64w+64), all gates:
// wf = 12 Mtiles x 8 Ktiles = 384 regs/lane, fully resident. No cross-WG
// traffic (r8 post-mortem: IC pair-handshake ~5us/step, dead end).
// LDS [chunk16B][batch] -> conflict-free; xg f32 double-buffered via
// global_load_lds; scr double-buffered -> ONE barrier per step.
// D = mfma(Wfrag, hfrag): row=gate (lane>>4)*4+j, col=batch lane&15.
// =====================================================================
__launch_bounds__(256)
__global__ void k_scan1(const int* __restrict__ token,
                        const float* __restrict__ xgV,
                        const unsigned short* __restrict__ pack1,
                        const float* __restrict__ b_hh1,
                        const float* __restrict__ ln_g, const float* __restrict__ ln_b,
                        unsigned short* __restrict__ hn)
{
  __shared__ __align__(16) char hb[2][8192];     // [32 chunk][16 batch][8 bf16]
  __shared__ __align__(16) char xgb[2][49152];   // [192 chunk][16 batch][4 f32]
  __shared__ __align__(16) float lngb[512];      // ln_g | ln_b
  __shared__ __align__(16) float bnl[256];       // b_hh1 n-part
  __shared__ __align__(8)  float2 scr[2][4][16]; // [buf][wave][col] LN partials

  const int tid = threadIdx.x;
  const int w = tid>>6, lane = tid&63, hi = lane>>4, col = lane&15;
  const int b0 = blockIdx.x * 16;

  // persistent weight fragments: 12 Mtiles (r0..3,z0..3,n0..3) x 8 Kt = 384 regs
  short8 wf[12][8];
  #pragma unroll
  for (int ms=0; ms<12; ms++)
    #pragma unroll
    for (int kt=0; kt<8; kt++)
      wf[ms][kt] = *(const short8*)(pack1 + (size_t)(((w*12+ms)*8+kt)*64 + lane)*8);

  for (int i=tid; i<512; i+=256) lngb[i] = (i<256) ? ln_g[i] : ln_b[i-256];
  bnl[tid] = b_hh1[512 + tid];
  for (int i=tid; i<2048; i+=256) ((u32*)hb[0])[i] = 0;
  f32x4 hr0={0,0,0,0}, hr1={0,0,0,0}, hr2={0,0,0,0}, hr3={0,0,0,0};

  // stage xg(t): chunk c=(tid>>4)+16k (c = gate-quad g/4), batch tid&15
  auto stage = [&](int tt, int buf){
    int tok = token[tt*128 + b0 + (tid & 15)];
    const char* src = (const char*)xgV + (size_t)tok*3072 + ((tid>>4)<<4);
    char* dst = xgb[buf] + (tid>>4)*256 + (tid&15)*16;
    #pragma unroll
    for (int k=0;k<12;k++)
      gl_lds16(src + k*256, dst + k*4096);
  };
  stage(0, 0);
  __syncthreads();

  for (int t=0; t<1024; t++){
    const int cur = t & 1, nxt = cur ^ 1;
    if (t < 1023) stage(t+1, nxt);

    f32x4 acc[12];
    #pragma unroll
    for (int ms=0;ms<12;ms++) acc[ms] = (f32x4){0,0,0,0};
    #pragma unroll
    for (int kt=0;kt<8;kt++){
      short8 hf = *(const short8*)(hb[cur] + ((kt<<2)+hi)*256 + (col<<4));
      #pragma unroll
      for (int ms=0;ms<12;ms++)
        acc[ms] = __builtin_amdgcn_mfma_f32_16x16x32_bf16(wf[ms][kt], hf, acc[ms], 0, 0, 0);
    }

    float s1 = 0.f, s2 = 0.f;
    #pragma unroll
    for (int s=0;s<4;s++){
      const int ub = (w<<6) + (s<<4) + (hi<<2);   // unit base
      const char* xb = xgb[cur] + (col<<4);
      f32x4 xr  = *(const f32x4*)(xb + (size_t)(ub>>2)*256);
      f32x4 xz  = *(const f32x4*)(xb + (size_t)((ub>>2)+64)*256);
      f32x4 xn  = *(const f32x4*)(xb + (size_t)((ub>>2)+128)*256);
      f32x4 bn4 = *(const f32x4*)(bnl + ub);
      f32x4 h = (s==0)?hr0:(s==1)?hr1:(s==2)?hr2:hr3;
      #pragma unroll
      for (int j=0;j<4;j++){
        float r  = sigm(xr[j] + acc[s][j]);        // b_ih + b_hh_r/z folded in xgV
        float z  = sigm(xz[j] + acc[4+s][j]);
        float nn = tanh_(xn[j] + r*(acc[8+s][j] + bn4[j]));
        float hh = nn + z*(h[j] - nn);
        h[j] = hh; s1 += hh; s2 += hh*hh;
      }
      if (s==0) hr0=h; else if (s==1) hr1=h; else if (s==2) hr2=h; else hr3=h;
      *(u64*)(hb[nxt] + (ub>>3)*256 + (col<<4) + ((hi&1)<<3)) =
          pack4(h[0],h[1],h[2],h[3]);
    }
    s1 += __shfl_xor(s1, 16); s1 += __shfl_xor(s1, 32);
    s2 += __shfl_xor(s2, 16); s2 += __shfl_xor(s2, 32);
    if (hi == 0) scr[cur][w][col] = make_float2(s1, s2);
    __syncthreads();                               // ONE barrier per step

    float S1 = 0.f, S2 = 0.f;
    #pragma unroll
    for (int ww=0; ww<4; ww++){ float2 v = scr[cur][ww][col]; S1 += v.x; S2 += v.y; }
    float mu  = S1 * (1.0f/256.0f);
    float var = S2 * (1.0f/256.0f) - mu*mu;
    float rs  = rsqrtf(var + 256.0f);              // faithful eps=256
    #pragma unroll
    for (int s=0;s<4;s++){
      const int ub = (w<<6) + (s<<4) + (hi<<2);
      f32x4 g4 = *(const f32x4*)&lngb[ub];
      f32x4 e4 = *(const f32x4*)&lngb[256+ub];
      f32x4 h = (s==0)?hr0:(s==1)?hr1:(s==2)?hr2:hr3;
      u64 pk = pack4((h[0]-mu)*rs*g4[0] + e4[0],
                     (h[1]-mu)*rs*g4[1] + e4[1],
                     (h[2]-mu)*rs*g4[2] + e4[2],
                     (h[3]-mu)*rs*g4[3] + e4[3]);
      *(u64*)(hn + (size_t)(t*128 + b0 + col)*256 + ub) = pk;
    }
  }
}

// =====================================================================
// K3: xg2 = hn @ [w_ih2f; w_ih2b]^T. 512 wgs x 256 thr (4 waves).
// dir = blockIdx&1; wave w = slot s=4*dir+w of pack2 (96 G-rows each);
// 192 weight VGPRs/lane (resident per r8). 32 TB-tiles/wg.
// =====================================================================
__launch_bounds__(256)
__global__ void k_k3(const unsigned short* __restrict__ hn,
                     const unsigned short* __restrict__ pack2,
                     unsigned short* __restrict__ xg2f,
                     unsigned short* __restrict__ xg2b)
{
  const int tid = threadIdx.x;
  const int w = tid>>6, lane = tid&63, hi = lane>>4, col = lane&15;
  const int dir = blockIdx.x & 1;
  const int s = dir*4 + w;
  short8 wf[6][8];
  #pragma unroll
  for (int m=0;m<6;m++)
    #pragma unroll
    for (int kt=0;kt<8;kt++)
      wf[m][kt] = *(const short8*)(pack2 + (size_t)((s*48 + m*8 + kt)*64 + lane)*8);
  unsigned short* dst = dir ? xg2b : xg2f;

  for (int it=0; it<32; it++){
    int tb0 = (blockIdx.x>>1)*512 + it*16;
    const unsigned short* hrow = hn + (size_t)(tb0 + col)*256;
    f32x4 acc[6];
    #pragma unroll
    for (int m=0;m<6;m++) acc[m] = (f32x4){0,0,0,0};
    #pragma unroll
    for (int kt=0;kt<8;kt++){
      short8 hf = *(const short8*)(hrow + (kt<<5) + (hi<<3));
      #pragma unroll
      for (int m=0;m<6;m++)
        acc[m] = __builtin_amdgcn_mfma_f32_16x16x32_bf16(wf[m][kt], hf, acc[m], 0, 0, 0);
    }
    #pragma unroll
    for (int m=0;m<6;m++){
      int Gl = 96*w + (m<<4) + (hi<<2);
      u64 pk = pack4(acc[m][0], acc[m][1], acc[m][2], acc[m][3]);
      *(u64*)(dst + (size_t)(tb0 + col)*384 + Gl) = pk;
    }
  }
}

// =====================================================================
// K4: layer-2 scans, fwd+bwd concurrent. 16 wgs (8 fwd, 8 bwd) x 8 waves.
// Wave w owns hidden block 16w; w_hh2 in 48 VGPRs/lane (fits 128 cap). fp32 out.
// =====================================================================
__launch_bounds__(512)
__global__ void k_scan2(const unsigned short* __restrict__ xg2f,
                        const unsigned short* __restrict__ xg2b,
                        const unsigned short* __restrict__ pack3,
                        const float* __restrict__ b_ih2f, const float* __restrict__ b_hh2f,
                        const float* __restrict__ b_ih2b, const float* __restrict__ b_hh2b,
                        float* __restrict__ out)
{
  __shared__ __align__(16) char hb[2][4096];     // [16 chunk][16 batch][8 bf16]
  const int tid = threadIdx.x;
  const int w = tid>>6, lane = tid&63, hi = lane>>4, col = lane&15;
  const int blk = blockIdx.x;
  const int dir = blk >> 3;
  const int b0  = (blk & 7) * 16;
  const unsigned short* xg = dir ? xg2b : xg2f;
  const float* bi = dir ? b_ih2b : b_ih2f;
  const float* bh = dir ? b_hh2b : b_hh2f;

  short8 wf[3][4];
  #pragma unroll
  for (int m=0;m<3;m++)
    #pragma unroll
    for (int kt=0;kt<4;kt++)
      wf[m][kt] = *(const short8*)(pack3 + (size_t)(((dir*96 + w*12 + (m<<2) + kt))*64 + lane)*8);

  const int u = (w<<4) + (hi<<2);
  f32x4 bir = *(const f32x4*)(bi + u),        bhr = *(const f32x4*)(bh + u);
  f32x4 biz = *(const f32x4*)(bi + 128 + u),  bhz = *(const f32x4*)(bh + 128 + u);
  f32x4 bin = *(const f32x4*)(bi + 256 + u),  bhn = *(const f32x4*)(bh + 256 + u);
  f32x4 bcr = bir + bhr, bcz = biz + bhz;

  for (int i = tid; i < 1024; i += 512) ((u32*)hb[0])[i] = 0;
  f32x4 hcur = (f32x4){0,0,0,0};

  int te0 = dir ? 1023 : 0;
  const unsigned short* p0 = xg + (size_t)(te0*128 + b0 + col)*384;
  u64 xr_n = *(const u64*)(p0 + u);
  u64 xz_n = *(const u64*)(p0 + 128 + u);
  u64 xn_n = *(const u64*)(p0 + 256 + u);
  __syncthreads();

  for (int t=0; t<1024; t++){
    const int cur = t & 1, nxt = cur ^ 1;
    u64 xr = xr_n, xz = xz_n, xn = xn_n;
    if (t < 1023){
      int te1 = dir ? (1022 - t) : (t + 1);
      const unsigned short* p = xg + (size_t)(te1*128 + b0 + col)*384;
      xr_n = *(const u64*)(p + u);
      xz_n = *(const u64*)(p + 128 + u);
      xn_n = *(const u64*)(p + 256 + u);
    }
    f32x4 acc[3];
    #pragma unroll
    for (int m=0;m<3;m++) acc[m] = (f32x4){0,0,0,0};
    #pragma unroll
    for (int kt=0;kt<4;kt++){
      short8 hf = *(const short8*)(hb[cur] + ((kt<<2)+hi)*256 + (col<<4));
      #pragma unroll
      for (int m=0;m<3;m++)
        acc[m] = __builtin_amdgcn_mfma_f32_16x16x32_bf16(wf[m][kt], hf, acc[m], 0, 0, 0);
    }
    const int te = dir ? (1023 - t) : t;
    f32x4 hnew;
    #pragma unroll
    for (int j=0;j<4;j++){
      float r  = sigm(bf2f((unsigned short)(xr >> (16*j))) + bcr[j] + acc[0][j]);
      float z  = sigm(bf2f((unsigned short)(xz >> (16*j))) + bcz[j] + acc[1][j]);
      float nn = tanh_(bf2f((unsigned short)(xn >> (16*j))) + bin[j] + r*(acc[2][j] + bhn[j]));
      hnew[j] = nn + z*(hcur[j] - nn);
    }
    hcur = hnew;
    *(f32x4*)(out + (size_t)(te*128 + b0 + col)*256 + dir*128 + u) = hnew;
    u64 pk = pack4(hnew[0], hnew[1], hnew[2], hnew[3]);
    *(u64*)(hb[nxt] + ((u>>3))*256 + (col<<4) + ((hi&1)<<3)) = pk;
    __syncthreads();
  }
}

// =====================================================================
extern "C" void kernel_launch(void* const* d_in, const int* in_sizes, int n_in,
                              void* d_out, int out_size, void* d_ws, size_t ws_size,
                              hipStream_t stream)
{
  (void)in_sizes; (void)n_in; (void)out_size; (void)ws_size;
  const int*   token  = (const int*)  d_in[0];
  const float* emb    = (const float*)d_in[1];
  const float* w_ih1  = (const float*)d_in[2];
  const float* w_hh1  = (const float*)d_in[3];
  const float* b_ih1  = (const float*)d_in[4];
  const float* b_hh1  = (const float*)d_in[5];
  const float* ln_g   = (const float*)d_in[6];
  const float* ln_b   = (const float*)d_in[7];
  const float* w_ih2f = (const float*)d_in[8];
  const float* w_hh2f = (const float*)d_in[9];
  const float* b_ih2f = (const float*)d_in[10];
  const float* b_hh2f = (const float*)d_in[11];
  const float* w_ih2b = (const float*)d_in[12];
  const float* w_hh2b = (const float*)d_in[13];
  const float* b_ih2b = (const float*)d_in[14];
  const float* b_hh2b = (const float*)d_in[15];
  float* out = (float*)d_out;

  char* ws = (char*)d_ws;
  unsigned short* hn    = (unsigned short*)(ws);              //  67,108,864 B
  unsigned short* xg2f  = (unsigned short*)(ws + 67108864);   // 100,663,296 B
  unsigned short* xg2b  = (unsigned short*)(ws + 167772160);  // 100,663,296 B
  // xgV (f32, 393,216 B) aliases the START of the xg2b region: consumed by
  // k_scan1 before k_k3 writes xg2b.
  float*          xgV   = (float*)(ws + 167772160);
  unsigned short* pack1 = (unsigned short*)(ws + 268632064);  //     393,216 B
  unsigned short* pack2 = (unsigned short*)(ws + 269025280);  //     393,216 B
  unsigned short* pack3 = (unsigned short*)(ws + 269418496);  //     196,608 B

  hipLaunchKernelGGL(k_pack,  dim3(240), dim3(256), 0, stream,
                     w_hh1, w_ih2f, w_ih2b, w_hh2f, w_hh2b, pack1, pack2, pack3);
  hipLaunchKernelGGL(k_xgv,   dim3(384), dim3(256), 0, stream,
                     emb, w_ih1, b_ih1, b_hh1, xgV);
  hipLaunchKernelGGL(k_scan1, dim3(8),   dim3(256), 0, stream,
                     token, xgV, pack1, b_hh1, ln_g, ln_b, hn);
  hipLaunchKernelGGL(k_k3,    dim3(512), dim3(256), 0, stream,
                     hn, pack2, xg2f, xg2b);
  hipLaunchKernelGGL(k_scan2, dim3(16),  dim3(512), 0, stream,
                     xg2f, xg2b, pack3, b_ih2f, b_hh2f, b_ih2b, b_hh2b, out);
}

// Round 11
// 7019.926 us; speedup vs baseline: 1.0647x; 1.0578x over previous
//
#include <hip/hip_runtime.h>
#include <hip/hip_bf16.h>
#include <stdint.h>

typedef __attribute__((ext_vector_type(8))) short short8;   // 8 bf16 (4 VGPRs) MFMA frag
typedef __attribute__((ext_vector_type(4))) float f32x4;    // MFMA acc
typedef __attribute__((ext_vector_type(4))) unsigned int au4; // 128-bit AGPR-class value
typedef unsigned long long u64;
typedef unsigned int u32;

// ---------- helpers ----------
__device__ __forceinline__ float bf2f(unsigned short s){
  union { float f; u32 u; } v; v.u = ((u32)s) << 16; return v.f;
}
__device__ __forceinline__ unsigned short f2bf(float f){
  u32 u = __float_as_uint(f);
  u32 r = (u + 0x7fffu + ((u >> 16) & 1u)) >> 16;   // RNE
  return (unsigned short)r;
}
__device__ __forceinline__ float sigm(float x){ return 1.0f / (1.0f + __expf(-x)); }
__device__ __forceinline__ float tanh_(float x){ return 1.0f - 2.0f/(__expf(2.0f*x) + 1.0f); }
__device__ __forceinline__ u64 pack4(float a, float b, float c, float d){
  return (u64)f2bf(a) | ((u64)f2bf(b)<<16) | ((u64)f2bf(c)<<32) | ((u64)f2bf(d)<<48);
}
// async global->LDS, 16B per lane; dest must be wave-uniform base + lane*16
__device__ __forceinline__ void gl_lds16(const void* g, void* l){
  __builtin_amdgcn_global_load_lds(
      (const __attribute__((address_space(1))) unsigned int*)g,
      (__attribute__((address_space(3))) unsigned int*)l, 16, 0, 0);
}

// =====================================================================
// K0a: pack weights into MFMA fragment layout (bf16)
//  frag convention (16x16x32): lane l elem j -> [nonK = l&15][k = (l>>4)*8 + j]
// pack1: w_hh1 (768x256): 4 wave-slots, slot w owns units [64w,64w+64);
//        frag f = w*96 + (G*4+s)*8 + kt; row g = G*256 + 64w + 16s + (l&15)
// pack2: [w_ih2f; w_ih2b] as 768 G-rows: 8 slots, slot s owns G [96s,96s+96)
// pack3: per-dir w_hh2 (384x128), 8 waves, wave w owns unit block 16w
// =====================================================================
__global__ void k_pack(const float* __restrict__ w_hh1,
                       const float* __restrict__ w_ih2f, const float* __restrict__ w_ih2b,
                       const float* __restrict__ w_hh2f, const float* __restrict__ w_hh2b,
                       unsigned short* __restrict__ pack1,
                       unsigned short* __restrict__ pack2,
                       unsigned short* __restrict__ pack3)
{
  int tid = blockIdx.x*256 + threadIdx.x;
  const float* src;
  unsigned short* dst;
  long idx;
  if (tid < 24576){
    int f = tid>>6, l = tid&63;
    int w = f/96, rem = f%96, kt = rem&7, ms = rem>>3, G = ms>>2, s = ms&3;
    int g  = (G<<8) + (w<<6) + (s<<4) + (l&15);
    int kb = (kt<<5) + ((l>>4)<<3);
    src = w_hh1 + (size_t)g*256 + kb;
    dst = pack1; idx = tid;
  } else if (tid < 49152){
    int t2 = tid - 24576;
    int f = t2>>6, l = t2&63;
    int s = f/48, rem = f%48, m = rem>>3, kt = rem&7;
    int G  = 96*s + (m<<4) + (l&15);
    int kb = (kt<<5) + ((l>>4)<<3);
    const float* W = (G < 384) ? w_ih2f : w_ih2b;
    src = W + (size_t)(G % 384)*256 + kb;
    dst = pack2; idx = t2;
  } else {
    int t3 = tid - 49152;
    int f = t3>>6, l = t3&63;
    int dir = f/96, r96 = f%96, w = r96/12, r12 = r96%12, m = r12>>2, kt = r12&3;
    int Grow = (m<<7) + (w<<4) + (l&15);
    int kb = (kt<<5) + ((l>>4)<<3);
    src = (dir ? w_hh2b : w_hh2f) + (size_t)Grow*128 + kb;
    dst = pack3; idx = t3;
  }
  u64 lo = (u64)f2bf(src[0]) | ((u64)f2bf(src[1])<<16) | ((u64)f2bf(src[2])<<32) | ((u64)f2bf(src[3])<<48);
  u64 hi = (u64)f2bf(src[4]) | ((u64)f2bf(src[5])<<16) | ((u64)f2bf(src[6])<<32) | ((u64)f2bf(src[7])<<48);
  *(u64*)(dst + (size_t)idx*8)     = lo;
  *(u64*)(dst + (size_t)idx*8 + 4) = hi;
}

// =====================================================================
// K0b: xgV[v][g] = emb[v,:]·w_ih1[g,:] + b_ih1[g] + (g<512 ? b_hh1[g] : 0)
// =====================================================================
__global__ void k_xgv(const float* __restrict__ emb, const float* __restrict__ w_ih1,
                      const float* __restrict__ b_ih1, const float* __restrict__ b_hh1,
                      float* __restrict__ xgV)
{
  int tid = blockIdx.x*256 + threadIdx.x;        // 98304 total
  int v = tid / 768, g = tid % 768;
  float s = b_ih1[g] + (g < 512 ? b_hh1[g] : 0.0f);
  const f32x4* e4 = (const f32x4*)(emb   + (size_t)v*312);
  const f32x4* w4 = (const f32x4*)(w_ih1 + (size_t)g*312);
  #pragma unroll 4
  for (int i=0;i<78;i++){
    f32x4 a = e4[i], b = w4[i];
    s += a[0]*b[0] + a[1]*b[1] + a[2]*b[2] + a[3]*b[3];
  }
  xgV[tid] = s;
}

// =====================================================================
// K1: layer-1 scan. 8 wgs x 256 thr (4 waves = 1 wave/SIMD -> 256 arch +
// 256 AGPR per wave). Wave w owns units [64w,64w+64).
// r,z weights: 64 fragments held as "a"-register-class VALUES (tied-operand
// empty asm) -> compiler-managed AGPR liveness. r10 post-mortem: clobber
// pinning was unsound (compiler spilled arch VGPRs into "free" AGPRs between
// asm statements, corrupting weights -> NaN). With "a"-class values the
// allocator knows they're live and cannot touch them.
// n weights: 32 frags in arch VGPRs via the normal intrinsic.
// One barrier per step. LDS [chunk16B][batch] -> conflict-free ds_read_b128.
// D = mfma(Wfrag, hfrag): row=gate (lane>>4)*4+j, col=batch lane&15.
// =====================================================================
__launch_bounds__(256)
__global__ void k_scan1(const int* __restrict__ token,
                        const float* __restrict__ xgV,
                        const unsigned short* __restrict__ pack1,
                        const float* __restrict__ b_hh1,
                        const float* __restrict__ ln_g, const float* __restrict__ ln_b,
                        unsigned short* __restrict__ hn)
{
  __shared__ __align__(16) char hb[2][8192];     // [32 chunk][16 batch][8 bf16]
  __shared__ __align__(16) char xgb[2][49152];   // [192 chunk][16 batch][4 f32]
  __shared__ __align__(16) float lngb[512];      // ln_g | ln_b
  __shared__ __align__(16) float bnl[256];       // b_hh1 n-part
  __shared__ __align__(8)  float2 scr[2][4][16]; // [buf][wave][col] LN partials

  const int tid = threadIdx.x;
  const int w = tid>>6, lane = tid&63, hi = lane>>4, col = lane&15;
  const int b0 = blockIdx.x * 16;

  // r,z weight frags -> 64 AGPR-class values (256 AGPRs), compiler-managed.
  // pack frag q = (G*4+m)*8+kt; r: q = m*8+kt, z: q = 32+m*8+kt.
  const char* wpb = (const char*)pack1 + ((size_t)w*96*64 + lane)*16;
  au4 wrz[64];
  #pragma unroll
  for (int q=0;q<64;q++){
    union{ short8 s; au4 v; } t;
    t.s = *(const short8*)(wpb + (size_t)q*1024);
    asm volatile("" : "=a"(wrz[q]) : "0"(t.v));   // force AGPR class, keep live
  }

  // n weights (Mtiles 8..11) -> arch VGPRs, 32 frags = 128 regs
  short8 wf[4][8];
  #pragma unroll
  for (int s=0; s<4; s++)
    #pragma unroll
    for (int kt=0; kt<8; kt++)
      wf[s][kt] = *(const short8*)(pack1 + (size_t)(((w*96 + 64 + s*8 + kt))*64 + lane)*8);

  for (int i=tid; i<512; i+=256) lngb[i] = (i<256) ? ln_g[i] : ln_b[i-256];
  bnl[tid] = b_hh1[512 + tid];
  for (int i=tid; i<2048; i+=256) ((u32*)hb[0])[i] = 0;
  f32x4 hr[4];
  #pragma unroll
  for (int s=0;s<4;s++) hr[s] = (f32x4){0,0,0,0};

  auto stage = [&](int tt, int buf){
    int tok = token[tt*128 + b0 + (tid & 15)];
    const char* src = (const char*)xgV + (size_t)tok*3072 + ((tid>>4)<<4);
    char* dst = xgb[buf] + (tid>>4)*256 + (tid&15)*16;
    #pragma unroll
    for (int k=0;k<12;k++)
      gl_lds16(src + k*256, dst + k*4096);
  };
  stage(0, 0);
  __syncthreads();

  for (int t=0; t<1024; t++){
    const int cur = t & 1, nxt = cur ^ 1;
    if (t < 1023) stage(t+1, nxt);

    const char* hbc = hb[cur];
    f32x4 aR[4], aZ[4], accN[4];
    #pragma unroll
    for (int s=0;s<4;s++){
      aR[s] = (f32x4){0,0,0,0}; aZ[s] = (f32x4){0,0,0,0}; accN[s] = (f32x4){0,0,0,0};
    }

    #pragma unroll
    for (int kt=0;kt<8;kt++){
      short8 hf = *(const short8*)(hbc + ((kt<<2)+hi)*256 + (col<<4));
      #pragma unroll
      for (int m=0;m<4;m++){
        asm volatile("v_mfma_f32_16x16x32_bf16 %0, %1, %2, %0"
                     : "+v"(aR[m]) : "a"(wrz[m*8+kt]), "v"(hf));
        asm volatile("v_mfma_f32_16x16x32_bf16 %0, %1, %2, %0"
                     : "+v"(aZ[m]) : "a"(wrz[32+m*8+kt]), "v"(hf));
        accN[m] = __builtin_amdgcn_mfma_f32_16x16x32_bf16(wf[m][kt], hf, accN[m], 0, 0, 0);
      }
    }
    asm volatile("s_nop 7\n\ts_nop 7");            // asm-MFMA D -> VALU hazard guard

    float s1 = 0.f, s2 = 0.f;
    #pragma unroll
    for (int s=0;s<4;s++){
      const int ub = (w<<6) + (s<<4) + (hi<<2);
      const char* xb = xgb[cur] + (col<<4);
      f32x4 xr  = *(const f32x4*)(xb + (size_t)(ub>>2)*256);
      f32x4 xz  = *(const f32x4*)(xb + (size_t)((ub>>2)+64)*256);
      f32x4 xn  = *(const f32x4*)(xb + (size_t)((ub>>2)+128)*256);
      f32x4 bn4 = *(const f32x4*)(bnl + ub);
      #pragma unroll
      for (int j=0;j<4;j++){
        float r  = sigm(xr[j] + aR[s][j]);         // b_ih + b_hh_r/z folded in xgV
        float z  = sigm(xz[j] + aZ[s][j]);
        float nn = tanh_(xn[j] + r*(accN[s][j] + bn4[j]));
        float hh = nn + z*(hr[s][j] - nn);
        hr[s][j] = hh; s1 += hh; s2 += hh*hh;
      }
      *(u64*)(hb[nxt] + (ub>>3)*256 + (col<<4) + ((hi&1)<<3)) =
          pack4(hr[s][0],hr[s][1],hr[s][2],hr[s][3]);
    }
    s1 += __shfl_xor(s1, 16); s1 += __shfl_xor(s1, 32);
    s2 += __shfl_xor(s2, 16); s2 += __shfl_xor(s2, 32);
    if (hi == 0) scr[cur][w][col] = make_float2(s1, s2);
    __syncthreads();                               // ONE barrier per step

    float S1 = 0.f, S2 = 0.f;
    #pragma unroll
    for (int ww=0; ww<4; ww++){ float2 v = scr[cur][ww][col]; S1 += v.x; S2 += v.y; }
    float mu  = S1 * (1.0f/256.0f);
    float var = S2 * (1.0f/256.0f) - mu*mu;
    float rs  = rsqrtf(var + 256.0f);              // faithful eps=256
    #pragma unroll
    for (int s=0;s<4;s++){
      const int ub = (w<<6) + (s<<4) + (hi<<2);
      f32x4 g4 = *(const f32x4*)&lngb[ub];
      f32x4 e4 = *(const f32x4*)&lngb[256+ub];
      u64 pk = pack4((hr[s][0]-mu)*rs*g4[0] + e4[0],
                     (hr[s][1]-mu)*rs*g4[1] + e4[1],
                     (hr[s][2]-mu)*rs*g4[2] + e4[2],
                     (hr[s][3]-mu)*rs*g4[3] + e4[3]);
      *(u64*)(hn + (size_t)(t*128 + b0 + col)*256 + ub) = pk;
    }
  }
}

// =====================================================================
// K3: xg2 = hn @ [w_ih2f; w_ih2b]^T. 512 wgs x 256 thr (4 waves).
// dir = blockIdx&1; wave w = slot s=4*dir+w of pack2 (96 G-rows each);
// 192 weight VGPRs/lane (fits the 256 arch cap). 32 TB-tiles/wg.
// =====================================================================
__launch_bounds__(256)
__global__ void k_k3(const unsigned short* __restrict__ hn,
                     const unsigned short* __restrict__ pack2,
                     unsigned short* __restrict__ xg2f,
                     unsigned short* __restrict__ xg2b)
{
  const int tid = threadIdx.x;
  const int w = tid>>6, lane = tid&63, hi = lane>>4, col = lane&15;
  const int dir = blockIdx.x & 1;
  const int s = dir*4 + w;
  short8 wf[6][8];
  #pragma unroll
  for (int m=0;m<6;m++)
    #pragma unroll
    for (int kt=0;kt<8;kt++)
      wf[m][kt] = *(const short8*)(pack2 + (size_t)((s*48 + m*8 + kt)*64 + lane)*8);
  unsigned short* dst = dir ? xg2b : xg2f;

  for (int it=0; it<32; it++){
    int tb0 = (blockIdx.x>>1)*512 + it*16;
    const unsigned short* hrow = hn + (size_t)(tb0 + col)*256;
    f32x4 acc[6];
    #pragma unroll
    for (int m=0;m<6;m++) acc[m] = (f32x4){0,0,0,0};
    #pragma unroll
    for (int kt=0;kt<8;kt++){
      short8 hf = *(const short8*)(hrow + (kt<<5) + (hi<<3));
      #pragma unroll
      for (int m=0;m<6;m++)
        acc[m] = __builtin_amdgcn_mfma_f32_16x16x32_bf16(wf[m][kt], hf, acc[m], 0, 0, 0);
    }
    #pragma unroll
    for (int m=0;m<6;m++){
      int Gl = 96*w + (m<<4) + (hi<<2);
      u64 pk = pack4(acc[m][0], acc[m][1], acc[m][2], acc[m][3]);
      *(u64*)(dst + (size_t)(tb0 + col)*384 + Gl) = pk;
    }
  }
}

// =====================================================================
// K4: layer-2 scans, fwd+bwd concurrent. 16 wgs (8 fwd, 8 bwd) x 8 waves.
// Wave w owns hidden block 16w; w_hh2 in 48 VGPRs/lane (fits 128 cap). fp32 out.
// =====================================================================
__launch_bounds__(512)
__global__ void k_scan2(const unsigned short* __restrict__ xg2f,
                        const unsigned short* __restrict__ xg2b,
                        const unsigned short* __restrict__ pack3,
                        const float* __restrict__ b_ih2f, const float* __restrict__ b_hh2f,
                        const float* __restrict__ b_ih2b, const float* __restrict__ b_hh2b,
                        float* __restrict__ out)
{
  __shared__ __align__(16) char hb[2][4096];     // [16 chunk][16 batch][8 bf16]
  const int tid = threadIdx.x;
  const int w = tid>>6, lane = tid&63, hi = lane>>4, col = lane&15;
  const int blk = blockIdx.x;
  const int dir = blk >> 3;
  const int b0  = (blk & 7) * 16;
  const unsigned short* xg = dir ? xg2b : xg2f;
  const float* bi = dir ? b_ih2b : b_ih2f;
  const float* bh = dir ? b_hh2b : b_hh2f;

  short8 wf[3][4];
  #pragma unroll
  for (int m=0;m<3;m++)
    #pragma unroll
    for (int kt=0;kt<4;kt++)
      wf[m][kt] = *(const short8*)(pack3 + (size_t)(((dir*96 + w*12 + (m<<2) + kt))*64 + lane)*8);

  const int u = (w<<4) + (hi<<2);
  f32x4 bir = *(const f32x4*)(bi + u),        bhr = *(const f32x4*)(bh + u);
  f32x4 biz = *(const f32x4*)(bi + 128 + u),  bhz = *(const f32x4*)(bh + 128 + u);
  f32x4 bin = *(const f32x4*)(bi + 256 + u),  bhn = *(const f32x4*)(bh + 256 + u);
  f32x4 bcr = bir + bhr, bcz = biz + bhz;

  for (int i = tid; i < 1024; i += 512) ((u32*)hb[0])[i] = 0;
  f32x4 hcur = (f32x4){0,0,0,0};

  int te0 = dir ? 1023 : 0;
  const unsigned short* p0 = xg + (size_t)(te0*128 + b0 + col)*384;
  u64 xr_n = *(const u64*)(p0 + u);
  u64 xz_n = *(const u64*)(p0 + 128 + u);
  u64 xn_n = *(const u64*)(p0 + 256 + u);
  __syncthreads();

  for (int t=0; t<1024; t++){
    const int cur = t & 1, nxt = cur ^ 1;
    u64 xr = xr_n, xz = xz_n, xn = xn_n;
    if (t < 1023){
      int te1 = dir ? (1022 - t) : (t + 1);
      const unsigned short* p = xg + (size_t)(te1*128 + b0 + col)*384;
      xr_n = *(const u64*)(p + u);
      xz_n = *(const u64*)(p + 128 + u);
      xn_n = *(const u64*)(p + 256 + u);
    }
    f32x4 acc[3];
    #pragma unroll
    for (int m=0;m<3;m++) acc[m] = (f32x4){0,0,0,0};
    #pragma unroll
    for (int kt=0;kt<4;kt++){
      short8 hf = *(const short8*)(hb[cur] + ((kt<<2)+hi)*256 + (col<<4));
      #pragma unroll
      for (int m=0;m<3;m++)
        acc[m] = __builtin_amdgcn_mfma_f32_16x16x32_bf16(wf[m][kt], hf, acc[m], 0, 0, 0);
    }
    const int te = dir ? (1023 - t) : t;
    f32x4 hnew;
    #pragma unroll
    for (int j=0;j<4;j++){
      float r  = sigm(bf2f((unsigned short)(xr >> (16*j))) + bcr[j] + acc[0][j]);
      float z  = sigm(bf2f((unsigned short)(xz >> (16*j))) + bcz[j] + acc[1][j]);
      float nn = tanh_(bf2f((unsigned short)(xn >> (16*j))) + bin[j] + r*(acc[2][j] + bhn[j]));
      hnew[j] = nn + z*(hcur[j] - nn);
    }
    hcur = hnew;
    *(f32x4*)(out + (size_t)(te*128 + b0 + col)*256 + dir*128 + u) = hnew;
    u64 pk = pack4(hnew[0], hnew[1], hnew[2], hnew[3]);
    *(u64*)(hb[nxt] + ((u>>3))*256 + (col<<4) + ((hi&1)<<3)) = pk;
    __syncthreads();
  }
}

// =====================================================================
extern "C" void kernel_launch(void* const* d_in, const int* in_sizes, int n_in,
                              void* d_out, int out_size, void* d_ws, size_t ws_size,
                              hipStream_t stream)
{
  (void)in_sizes; (void)n_in; (void)out_size; (void)ws_size;
  const int*   token  = (const int*)  d_in[0];
  const float* emb    = (const float*)d_in[1];
  const float* w_ih1  = (const float*)d_in[2];
  const float* w_hh1  = (const float*)d_in[3];
  const float* b_ih1  = (const float*)d_in[4];
  const float* b_hh1  = (const float*)d_in[5];
  const float* ln_g   = (const float*)d_in[6];
  const float* ln_b   = (const float*)d_in[7];
  const float* w_ih2f = (const float*)d_in[8];
  const float* w_hh2f = (const float*)d_in[9];
  const float* b_ih2f = (const float*)d_in[10];
  const float* b_hh2f = (const float*)d_in[11];
  const float* w_ih2b = (const float*)d_in[12];
  const float* w_hh2b = (const float*)d_in[13];
  const float* b_ih2b = (const float*)d_in[14];
  const float* b_hh2b = (const float*)d_in[15];
  float* out = (float*)d_out;

  char* ws = (char*)d_ws;
  unsigned short* hn    = (unsigned short*)(ws);              //  67,108,864 B
  unsigned short* xg2f  = (unsigned short*)(ws + 67108864);   // 100,663,296 B
  unsigned short* xg2b  = (unsigned short*)(ws + 167772160);  // 100,663,296 B
  // xgV (f32, 393,216 B) aliases the START of the xg2b region: consumed by
  // k_scan1 before k_k3 writes xg2b.
  float*          xgV   = (float*)(ws + 167772160);
  unsigned short* pack1 = (unsigned short*)(ws + 268632064);  //     393,216 B
  unsigned short* pack2 = (unsigned short*)(ws + 269025280);  //     393,216 B
  unsigned short* pack3 = (unsigned short*)(ws + 269418496);  //     196,608 B

  hipLaunchKernelGGL(k_pack,  dim3(240), dim3(256), 0, stream,
                     w_hh1, w_ih2f, w_ih2b, w_hh2f, w_hh2b, pack1, pack2, pack3);
  hipLaunchKernelGGL(k_xgv,   dim3(384), dim3(256), 0, stream,
                     emb, w_ih1, b_ih1, b_hh1, xgV);
  hipLaunchKernelGGL(k_scan1, dim3(8),   dim3(256), 0, stream,
                     token, xgV, pack1, b_hh1, ln_g, ln_b, hn);
  hipLaunchKernelGGL(k_k3,    dim3(512), dim3(256), 0, stream,
                     hn, pack2, xg2f, xg2b);
  hipLaunchKernelGGL(k_scan2, dim3(16),  dim3(512), 0, stream,
                     xg2f, xg2b, pack3, b_ih2f, b_hh2f, b_ih2b, b_hh2b, out);
}